// Round 1
// baseline (3743.996 us; speedup 1.0000x reference)
//
#include <hip/hip_runtime.h>

#define EPSBN 2e-5f

// ---------------------------------------------------------------------------
// Lift (R1 -> R1xR+) conv K=79 fused with pool4.
// x: [8,1,32768], w1: [51,79] -> y1: [8,51,9,8192]
// out[b,c,s,l1] = max_{p=0..3} (1/2^s) * sum_k x[b, 4*l1+p + (k-39)*2^s] * w1[c,k]
// Thread computes 8 conv outputs spaced d apart (sliding register window:
// 1 new load per 8 FMAs), block tiles 2048 conv positions -> 512 pooled.
// ---------------------------------------------------------------------------
__global__ __launch_bounds__(256) void lift_pool_kernel(
    const float* __restrict__ x, const float* __restrict__ w1,
    float* __restrict__ y1) {
  const int tile = blockIdx.x;            // 16 tiles of 2048 conv positions
  const int c = blockIdx.y / 9;
  const int s = blockIdx.y % 9;
  const int b = blockIdx.z;
  const int d = 1 << s;
  const int l0 = tile * 2048;
  const float* xb = x + (size_t)b * 32768;
  const float* wr = w1 + c * 79;

  __shared__ float tilebuf[2048];

  const int t = threadIdx.x;
  const int q = t & (d - 1);
  const int j = t >> s;
  const int base = l0 + q + (j << 3) * d;   // outputs at base + r*d, r=0..7

  float acc[8];
  float win[8];
#pragma unroll
  for (int r = 0; r < 8; ++r) acc[r] = 0.f;
  // preload taps offsets o = -39..-32 ; slot = o mod 8 = (i+1)&7
#pragma unroll
  for (int i0 = 0; i0 < 8; ++i0) {
    int pos = base + (i0 - 39) * d;
    win[(i0 + 1) & 7] = (pos >= 0 && pos < 32768) ? xb[pos] : 0.f;
  }
#pragma unroll
  for (int ko = 0; ko < 10; ++ko) {
#pragma unroll
    for (int kj = 0; kj < 8; ++kj) {
      const int k = ko * 8 + kj;
      const float wk = (k < 79) ? wr[k] : 0.f;
#pragma unroll
      for (int r = 0; r < 8; ++r)
        acc[r] += wk * win[(kj + r + 1) & 7];
      // slide window: load offset (k-31) into slot (k+1)&7
      int pos = base + (k - 31) * d;
      win[(kj + 1) & 7] = (pos >= 0 && pos < 32768) ? xb[pos] : 0.f;
    }
  }
#pragma unroll
  for (int r = 0; r < 8; ++r)
    tilebuf[q + ((j << 3) + r) * d] = acc[r];
  __syncthreads();
  const float inv = 1.f / (float)d;
  float* yrow = y1 + (((size_t)b * 51 + c) * 9 + s) * 8192 + tile * 512;
  for (int p = t; p < 512; p += 256) {
    float v = fmaxf(fmaxf(tilebuf[4 * p], tilebuf[4 * p + 1]),
                    fmaxf(tilebuf[4 * p + 2], tilebuf[4 * p + 3]));
    yrow[p] = v * inv;
  }
}

// ---------------------------------------------------------------------------
// Per-channel sum/sumsq over [B,C,HL]; grid (C,B); atomicAdd into st[c], st[512+c]
// ---------------------------------------------------------------------------
__global__ __launch_bounds__(256) void stats_kernel(
    const float* __restrict__ Y, float* __restrict__ st, int C, int HL) {
  const int c = blockIdx.x, b = blockIdx.y;
  const float* p = Y + ((size_t)b * C + c) * HL;
  float s = 0.f, q = 0.f;
  for (int i = threadIdx.x; i < HL; i += 256) {
    float v = p[i];
    s += v;
    q += v * v;
  }
#pragma unroll
  for (int off = 32; off > 0; off >>= 1) {
    s += __shfl_down(s, off, 64);
    q += __shfl_down(q, off, 64);
  }
  __shared__ float ls[4], lq[4];
  const int wid = threadIdx.x >> 6, lane = threadIdx.x & 63;
  if (lane == 0) { ls[wid] = s; lq[wid] = q; }
  __syncthreads();
  if (threadIdx.x == 0) {
    atomicAdd(&st[c], ls[0] + ls[1] + ls[2] + ls[3]);
    atomicAdd(&st[512 + c], lq[0] + lq[1] + lq[2] + lq[3]);
  }
}

// ---------------------------------------------------------------------------
// BN(train) + ReLU + pool4.  Y:[B,C,H,Lin] -> Z:[B,C,H,Lin/4]
// ---------------------------------------------------------------------------
__global__ __launch_bounds__(256) void bnrelu_pool_kernel(
    const float* __restrict__ Y, const float* __restrict__ st,
    const float* __restrict__ g, const float* __restrict__ bb,
    float* __restrict__ Z, int C, int H, int Lin, float invN,
    unsigned int total) {
  unsigned int idx = blockIdx.x * 256u + threadIdx.x;
  if (idx >= total) return;
  const unsigned int Lo = (unsigned int)(Lin >> 2);
  unsigned int lo = idx % Lo;
  unsigned int r1 = idx / Lo;
  unsigned int h = r1 % (unsigned int)H;
  unsigned int r2 = r1 / (unsigned int)H;
  unsigned int c = r2 % (unsigned int)C;
  unsigned int b = r2 / (unsigned int)C;
  float m = st[c] * invN;
  float v = st[512 + c] * invN - m * m;
  float sc = g[c] * rsqrtf(v + EPSBN);
  float bi = bb[c] - m * sc;
  const float* p = Y + (((size_t)b * C + c) * H + h) * Lin + 4u * lo;
  float r = fmaxf(fmaxf(p[0], p[1]), fmaxf(p[2], p[3]));
  // sc can be any sign in general -> compute max over affine values directly
  float a0 = p[0] * sc + bi, a1 = p[1] * sc + bi;
  float a2 = p[2] * sc + bi, a3 = p[3] * sc + bi;
  r = fmaxf(fmaxf(a0, a1), fmaxf(a2, a3));
  r = fmaxf(r, 0.f);
  Z[idx] = r;
}

// ---------------------------------------------------------------------------
// GConvGG: X:[B,Ci,Hin,L] (raw; optional input BN+ReLU fused on load),
// W:[Co,Ci,NK,3] -> Y:[B,Co,Hin-NK+1,L]
// Y[b,co,s,l] = sum_i sum_ci sum_k relu(bn(X))[b,ci,s+i,l+(k-1)*d_i] * W / d_i,
// d_i = 2^(s+i), zero padding applied after bn+relu (handled in staging).
// Block: 256 threads = G groups of TL lanes; each thread accumulates COT co's.
// ---------------------------------------------------------------------------
template <int NK, int TL, int MAXD, int CHUNK, int COT>
__global__ __launch_bounds__(256) void gg_conv_kernel(
    const float* __restrict__ X, const float* __restrict__ W,
    const float* __restrict__ stIn, const float* __restrict__ gIn,
    const float* __restrict__ bIn, float invNIn, float* __restrict__ Y,
    int Ci, int Co, int Hin, int L) {
  constexpr int G = 256 / TL;
  constexpr int SPAN = G * COT;
  constexpr int PITCH = TL + 2 * MAXD;

  const int lChunks = L / TL;
  const int lc = blockIdx.x % lChunks;
  const int cochunk = blockIdx.x / lChunks;
  const int s = blockIdx.y;
  const int b = blockIdx.z;
  const int Hout = Hin - NK + 1;
  const int l0 = lc * TL;
  const int tid = threadIdx.x;
  const int lt = tid % TL;
  const int gq = tid / TL;
  const int coBase = cochunk * SPAN + gq * COT;

  __shared__ float rows[CHUNK * NK][PITCH];
  __shared__ float insc[416], inbi[416];

  for (int c = tid; c < Ci; c += 256) {
    float sc = 1.f, bi = 0.f;
    if (stIn) {
      float m = stIn[c] * invNIn;
      float v = stIn[512 + c] * invNIn - m * m;
      sc = gIn[c] * rsqrtf(v + EPSBN);
      bi = bIn[c] - m * sc;
    }
    insc[c] = sc;
    inbi[c] = bi;
  }
  __syncthreads();

  float acc[COT];
#pragma unroll
  for (int r = 0; r < COT; ++r) acc[r] = 0.f;

  for (int ci0 = 0; ci0 < Ci; ci0 += CHUNK) {
    // ---- stage CHUNK x NK rows into LDS (bn+relu+1/d folded, zero-padded)
    for (int cc = 0; cc < CHUNK; ++cc) {
      const int ci = ci0 + cc;
      const bool civ = ci < Ci;
      const float sc = civ ? insc[ci] : 0.f;
      const float bi = civ ? inbi[ci] : 0.f;
#pragma unroll
      for (int i = 0; i < NK; ++i) {
        const int dd = 1 << (s + i);
        const float inv = 1.f / (float)dd;
        const int Wd = TL + 2 * dd;
        const float* src =
            X + (((size_t)b * Ci + (civ ? ci : 0)) * Hin + (s + i)) * L;
        for (int r = tid; r < Wd; r += 256) {
          const int l = l0 - dd + r;
          float v = 0.f;
          if (civ && l >= 0 && l < L)
            v = fmaxf(src[l] * sc + bi, 0.f) * inv;
          rows[cc * NK + i][r] = v;
        }
      }
    }
    __syncthreads();
    // ---- compute
    for (int cc = 0; cc < CHUNK; ++cc) {
      const int ci = min(ci0 + cc, Ci - 1);  // rows are zero if overrun
#pragma unroll
      for (int i = 0; i < NK; ++i) {
        const int dd = 1 << (s + i);
        const float* row = rows[cc * NK + i];
        const float xm = row[lt];
        const float xc = row[lt + dd];
        const float xp = row[lt + 2 * dd];
#pragma unroll
        for (int r = 0; r < COT; ++r) {
          const int co = min(coBase + r, Co - 1);
          const float* w3 = W + (((size_t)co * Ci + ci) * NK + i) * 3;
          acc[r] += w3[0] * xm + w3[1] * xc + w3[2] * xp;
        }
      }
    }
    __syncthreads();
  }
#pragma unroll
  for (int r = 0; r < COT; ++r) {
    const int co = coBase + r;
    if (co < Co)
      Y[(((size_t)b * Co + co) * Hout + s) * L + l0 + lt] = acc[r];
  }
}

// ---------------------------------------------------------------------------
// Final: bn10+relu on y10 [8,408,1,32], mean over L, 1x1 classifier w11[10,408]
// ---------------------------------------------------------------------------
__global__ __launch_bounds__(256) void final_kernel(
    const float* __restrict__ Y, const float* __restrict__ st,
    const float* __restrict__ g, const float* __restrict__ bb,
    const float* __restrict__ w11, float* __restrict__ out) {
  const int b = blockIdx.x;
  const int tid = threadIdx.x;
  __shared__ float tch[408];
  for (int c = tid; c < 408; c += 256) {
    float m = st[c] * (1.f / 256.f);
    float v = st[512 + c] * (1.f / 256.f) - m * m;
    float sc = g[c] * rsqrtf(v + EPSBN);
    float bi = bb[c] - m * sc;
    const float* p = Y + ((size_t)b * 408 + c) * 32;
    float ssum = 0.f;
#pragma unroll
    for (int l = 0; l < 32; ++l) ssum += fmaxf(p[l] * sc + bi, 0.f);
    tch[c] = ssum * (1.f / 32.f);
  }
  __syncthreads();
  if (tid < 10) {
    float ssum = 0.f;
    for (int c = 0; c < 408; ++c) ssum += w11[tid * 408 + c] * tch[c];
    out[b * 10 + tid] = ssum;
  }
}

// ---------------------------------------------------------------------------
extern "C" void kernel_launch(void* const* d_in, const int* in_sizes, int n_in,
                              void* d_out, int out_size, void* d_ws,
                              size_t ws_size, hipStream_t stream) {
  const float* x = (const float*)d_in[0];
  const float* w1 = (const float*)d_in[1];
  const float* w2 = (const float*)d_in[2];
  const float* w3 = (const float*)d_in[3];
  const float* w4 = (const float*)d_in[4];
  const float* w5 = (const float*)d_in[5];
  const float* w6 = (const float*)d_in[6];
  const float* w7 = (const float*)d_in[7];
  const float* w8 = (const float*)d_in[8];
  const float* w9 = (const float*)d_in[9];
  const float* w10 = (const float*)d_in[10];
  const float* w11 = (const float*)d_in[11];
  const float* gg[11];
  const float* bbv[11];
  for (int i = 1; i <= 10; ++i) {
    gg[i] = (const float*)d_in[12 + 2 * (i - 1)];
    bbv[i] = (const float*)d_in[12 + 2 * (i - 1) + 1];
  }

  float* ws = (float*)d_ws;
  // arenas (in floats)
  const size_t AR0 = 0;
  const size_t AR1 = 30081024;         // y1 size 8*51*9*8192
  const size_t STATS = 37601280;       // AR1 + 7520256 (z1 size)
  float* y1 = ws + AR0;
  float* z1 = ws + AR1;
  float* y2 = ws + AR0;
  float* y3 = ws + AR0 + 5849088;
  float* z3 = ws + AR1;
  float* y4 = ws + AR0;
  float* y5 = ws + AR0 + 2088960;
  float* z5 = ws + AR1;
  float* y6 = ws + AR0;
  float* y7 = ws + AR0 + 626688;
  float* y8 = ws + AR0 + 1253376;
  float* z8 = ws + AR1;
  float* y9 = ws + AR0;
  float* y10 = ws + AR0 + 104448;
  float* st[11];
  for (int i = 1; i <= 10; ++i) st[i] = ws + STATS + (size_t)(i - 1) * 1024;

  hipMemsetAsync((void*)(ws + STATS), 0, 10 * 1024 * sizeof(float), stream);

  // ---- lift + pool4 : [8,51,9,8192]
  lift_pool_kernel<<<dim3(16, 459, 8), 256, 0, stream>>>(x, w1, y1);
  stats_kernel<<<dim3(51, 8), 256, 0, stream>>>(y1, st[1], 51, 9 * 8192);
  {
    unsigned int tot = 8u * 51 * 9 * 2048;
    bnrelu_pool_kernel<<<(tot + 255) / 256, 256, 0, stream>>>(
        y1, st[1], gg[1], bbv[1], z1, 51, 9, 8192, 1.f / 589824.f, tot);
  }
  // ---- gg2: 51->51, H 9->7, L=2048
  gg_conv_kernel<3, 256, 256, 4, 8><<<dim3(7 * 8, 7, 8), 256, 0, stream>>>(
      z1, w2, nullptr, nullptr, nullptr, 0.f, y2, 51, 51, 9, 2048);
  stats_kernel<<<dim3(51, 8), 256, 0, stream>>>(y2, st[2], 51, 7 * 2048);
  // ---- gg3: 51->51, H7, L=2048 (bn2 fused on load)
  gg_conv_kernel<1, 256, 64, 8, 8><<<dim3(7 * 8, 7, 8), 256, 0, stream>>>(
      y2, w3, st[2], gg[2], bbv[2], 1.f / 114688.f, y3, 51, 51, 7, 2048);
  stats_kernel<<<dim3(51, 8), 256, 0, stream>>>(y3, st[3], 51, 7 * 2048);
  {
    unsigned int tot = 8u * 51 * 7 * 512;
    bnrelu_pool_kernel<<<(tot + 255) / 256, 256, 0, stream>>>(
        y3, st[3], gg[3], bbv[3], z3, 51, 7, 2048, 1.f / 114688.f, tot);
  }
  // ---- gg4: 51->102, H 7->5, L=512
  gg_conv_kernel<3, 256, 64, 4, 8><<<dim3(13 * 2, 5, 8), 256, 0, stream>>>(
      z3, w4, nullptr, nullptr, nullptr, 0.f, y4, 51, 102, 7, 512);
  stats_kernel<<<dim3(102, 8), 256, 0, stream>>>(y4, st[4], 102, 5 * 512);
  // ---- gg5: 102->102, H5, L=512
  gg_conv_kernel<1, 256, 16, 8, 8><<<dim3(13 * 2, 5, 8), 256, 0, stream>>>(
      y4, w5, st[4], gg[4], bbv[4], 1.f / 20480.f, y5, 102, 102, 5, 512);
  stats_kernel<<<dim3(102, 8), 256, 0, stream>>>(y5, st[5], 102, 5 * 512);
  {
    unsigned int tot = 8u * 102 * 5 * 128;
    bnrelu_pool_kernel<<<(tot + 255) / 256, 256, 0, stream>>>(
        y5, st[5], gg[5], bbv[5], z5, 102, 5, 512, 1.f / 20480.f, tot);
  }
  // ---- gg6: 102->204, H 5->3, L=128
  gg_conv_kernel<3, 128, 16, 4, 8><<<dim3(13, 3, 8), 256, 0, stream>>>(
      z5, w6, nullptr, nullptr, nullptr, 0.f, y6, 102, 204, 5, 128);
  stats_kernel<<<dim3(204, 8), 256, 0, stream>>>(y6, st[6], 204, 3 * 128);
  // ---- gg7: 204->204, H3, L=128
  gg_conv_kernel<1, 128, 4, 8, 8><<<dim3(13, 3, 8), 256, 0, stream>>>(
      y6, w7, st[6], gg[6], bbv[6], 1.f / 3072.f, y7, 204, 204, 3, 128);
  stats_kernel<<<dim3(204, 8), 256, 0, stream>>>(y7, st[7], 204, 3 * 128);
  // ---- gg8: 204->204, H3, L=128
  gg_conv_kernel<1, 128, 4, 8, 8><<<dim3(13, 3, 8), 256, 0, stream>>>(
      y7, w8, st[7], gg[7], bbv[7], 1.f / 3072.f, y8, 204, 204, 3, 128);
  stats_kernel<<<dim3(204, 8), 256, 0, stream>>>(y8, st[8], 204, 3 * 128);
  {
    unsigned int tot = 8u * 204 * 3 * 32;
    bnrelu_pool_kernel<<<(tot + 255) / 256, 256, 0, stream>>>(
        y8, st[8], gg[8], bbv[8], z8, 204, 3, 128, 1.f / 3072.f, tot);
  }
  // ---- gg9: 204->408, H 3->1, L=32
  gg_conv_kernel<3, 32, 4, 4, 8><<<dim3(7, 1, 8), 256, 0, stream>>>(
      z8, w9, nullptr, nullptr, nullptr, 0.f, y9, 204, 408, 3, 32);
  stats_kernel<<<dim3(408, 8), 256, 0, stream>>>(y9, st[9], 408, 32);
  // ---- gg10: 408->408, H1, L=32
  gg_conv_kernel<1, 32, 1, 8, 8><<<dim3(7, 1, 8), 256, 0, stream>>>(
      y9, w10, st[9], gg[9], bbv[9], 1.f / 256.f, y10, 408, 408, 1, 32);
  stats_kernel<<<dim3(408, 8), 256, 0, stream>>>(y10, st[10], 408, 32);
  // ---- bn10 + relu + mean + classifier
  final_kernel<<<dim3(8), 256, 0, stream>>>(y10, st[10], gg[10], bbv[10], w11,
                                            (float*)d_out);
}